// Round 1
// baseline (215.892 us; speedup 1.0000x reference)
//
#include <hip/hip_runtime.h>

typedef unsigned short u16;
typedef __attribute__((ext_vector_type(8))) short bf16x8;
typedef __attribute__((ext_vector_type(4))) float f32x4;

#define BM 128
#define BN 128
#define BK 64

__device__ __forceinline__ u16 f2bf(float f) {
    unsigned u = __float_as_uint(f);
    unsigned r = u + 0x7fffu + ((u >> 16) & 1u);
    return (u16)(r >> 16);
}
__device__ __forceinline__ float bf2f(u16 h) {
    return __uint_as_float(((unsigned)h) << 16);
}

__device__ __forceinline__ void gload_lds16(const u16* g, u16* l) {
    __builtin_amdgcn_global_load_lds(
        (__attribute__((address_space(1))) unsigned int*)(u16*)g,
        (__attribute__((address_space(3))) unsigned int*)l,
        16, 0, 0);
}

// ---------- conversions ----------
__global__ __launch_bounds__(256) void cvt_x_kernel(const float4* __restrict__ x,
                                                    ushort4* __restrict__ o, int n4) {
    int i = blockIdx.x * 256 + threadIdx.x;
    if (i < n4) {
        float4 f = x[i];
        ushort4 u;
        u.x = f2bf(f.x); u.y = f2bf(f.y); u.z = f2bf(f.z); u.w = f2bf(f.w);
        o[i] = u;
    }
}

// kernel[3][768][768] fp32 -> Wt[3*768][768] bf16 where Wt[j*768+o][d] = W[j][d][o]
__global__ __launch_bounds__(256) void cvt_w_kernel(const float* __restrict__ W,
                                                    u16* __restrict__ Wt) {
    __shared__ float t[32][33];
    const int j = blockIdx.z;
    const int d0 = blockIdx.x * 32, o0 = blockIdx.y * 32;
    const int tx = threadIdx.x, ty = threadIdx.y;
#pragma unroll
    for (int i = 0; i < 4; i++) {
        int d = d0 + ty + i * 8;
        t[ty + i * 8][tx] = W[((long)j * 768 + d) * 768 + o0 + tx];
    }
    __syncthreads();
#pragma unroll
    for (int i = 0; i < 4; i++) {
        int o = o0 + ty + i * 8;
        Wt[((long)j * 768 + o) * 768 + d0 + tx] = f2bf(t[tx][ty + i * 8]);
    }
}

// V[4*2048][768] bf16 -> Vt[4][768][2048] bf16
__global__ __launch_bounds__(256) void transpose_v_kernel(const u16* __restrict__ V,
                                                          u16* __restrict__ Vt) {
    __shared__ u16 t[32][33];
    const int b = blockIdx.z;
    const int s0 = blockIdx.x * 32, o0 = blockIdx.y * 32;
    const int tx = threadIdx.x, ty = threadIdx.y;
#pragma unroll
    for (int i = 0; i < 4; i++) {
        int s = s0 + ty + i * 8;
        t[ty + i * 8][tx] = V[((long)b * 2048 + s) * 768 + o0 + tx];
    }
    __syncthreads();
#pragma unroll
    for (int i = 0; i < 4; i++) {
        int o = o0 + ty + i * 8;
        Vt[((long)b * 768 + o) * 2048 + s0 + tx] = t[tx][ty + i * 8];
    }
}

// ---------- GEMM: C = A(MxK) * Bt(NxK)^T, bf16 in, fp32 acc ----------
// MODE 0: QKV epilogue -> bf16 into Q/K/V (contiguous segments of 6291456)
// MODE 1: scores -> bf16, scaled
// MODE 2: PV -> fp32 out
template <int MODE>
__global__ __launch_bounds__(256)
void gemm_bt_kernel(const u16* __restrict__ A, const u16* __restrict__ Bt,
                    u16* __restrict__ o16, float* __restrict__ o32,
                    int K, long sA, long sB, long sO, int ldc, float scale) {
    __shared__ u16 As[BM * BK];
    __shared__ u16 Bs[BN * BK];

    const int tid = threadIdx.x;
    const int lane = tid & 63;
    const int wave = tid >> 6;
    const int z = blockIdx.z;

    const u16* Ab = A + (long)z * sA + (long)blockIdx.x * BM * K;
    const u16* Bb = Bt + (long)z * sB + (long)blockIdx.y * BN * K;

    const int rl = lane >> 3;   // row within 8-row staging group
    const int pc = lane & 7;    // 16B chunk position within row
    const int q = lane >> 4;    // quad
    const int rA = lane & 15;
    const int wm = (wave >> 1) * 64;
    const int wn = (wave & 1) * 64;

    f32x4 acc[4][4];
    const f32x4 zero = {0.f, 0.f, 0.f, 0.f};
#pragma unroll
    for (int i = 0; i < 4; i++)
#pragma unroll
        for (int j = 0; j < 4; j++) acc[i][j] = zero;

    for (int k0 = 0; k0 < K; k0 += BK) {
        // stage 128x64 A-tile and B-tile via async global->LDS, 16B/lane
        // XOR swizzle: LDS row r position p holds global chunk p^(r&7)
#pragma unroll
        for (int t = 0; t < 4; ++t) {
            const int issue = wave + t * 4;      // wave-uniform
            const int row = issue * 8 + rl;
            const int gc = pc ^ (row & 7);
            gload_lds16(Ab + (long)row * K + k0 + gc * 8, &As[issue * 512]);
            gload_lds16(Bb + (long)row * K + k0 + gc * 8, &Bs[issue * 512]);
        }
        __syncthreads();
#pragma unroll
        for (int kk = 0; kk < BK; kk += 32) {
            const int gchunk = (kk >> 3) + q;    // desired global chunk index
            bf16x8 af[4], bfr[4];
#pragma unroll
            for (int mi = 0; mi < 4; ++mi) {
                const int R = wm + mi * 16 + rA;
                af[mi] = *(const bf16x8*)&As[R * 64 + ((gchunk ^ (R & 7)) << 3)];
            }
#pragma unroll
            for (int ni = 0; ni < 4; ++ni) {
                const int R = wn + ni * 16 + rA;
                bfr[ni] = *(const bf16x8*)&Bs[R * 64 + ((gchunk ^ (R & 7)) << 3)];
            }
#pragma unroll
            for (int mi = 0; mi < 4; ++mi)
#pragma unroll
                for (int ni = 0; ni < 4; ++ni)
                    acc[mi][ni] = __builtin_amdgcn_mfma_f32_16x16x32_bf16(
                        af[mi], bfr[ni], acc[mi][ni], 0, 0, 0);
        }
        __syncthreads();
    }

    // epilogue: C/D layout col=lane&15, row=quad*4+reg
    const int rowb = blockIdx.x * BM + wm + q * 4;
    const int colb = blockIdx.y * BN + wn + rA;
#pragma unroll
    for (int mi = 0; mi < 4; ++mi) {
#pragma unroll
        for (int ni = 0; ni < 4; ++ni) {
            const int col = colb + ni * 16;
#pragma unroll
            for (int r = 0; r < 4; ++r) {
                const int row = rowb + mi * 16 + r;
                const float v = acc[mi][ni][r];
                if (MODE == 0) {
                    const int seg = col / 768;  // block-uniform (tileN=128 divides 768)
                    o16[(long)seg * 6291456 + (long)row * ldc + (col - seg * 768)] = f2bf(v);
                } else if (MODE == 1) {
                    u16* dst = o16 + (long)z * sO;
                    dst[(long)row * ldc + col] = f2bf(v * scale);
                } else {
                    float* dst = o32 + (long)z * sO;
                    dst[(long)row * ldc + col] = v;
                }
            }
        }
    }
}

// ---------- softmax over rows of S[8192][2048] (bf16, in place) ----------
__global__ __launch_bounds__(256) void softmax_kernel(u16* __restrict__ S) {
    const long row = blockIdx.x;
    u16* p = S + row * 2048;
    const int t = threadIdx.x;
    float v[8];
    float mx = -1e30f;
#pragma unroll
    for (int i = 0; i < 8; i++) {
        v[i] = bf2f(p[t + i * 256]);
        mx = fmaxf(mx, v[i]);
    }
#pragma unroll
    for (int off = 32; off >= 1; off >>= 1) mx = fmaxf(mx, __shfl_xor(mx, off));
    __shared__ float red[4], red2[4];
    if ((t & 63) == 0) red[t >> 6] = mx;
    __syncthreads();
    mx = fmaxf(fmaxf(red[0], red[1]), fmaxf(red[2], red[3]));
    float s = 0.f;
#pragma unroll
    for (int i = 0; i < 8; i++) {
        v[i] = __expf(v[i] - mx);
        s += v[i];
    }
#pragma unroll
    for (int off = 32; off >= 1; off >>= 1) s += __shfl_xor(s, off);
    if ((t & 63) == 0) red2[t >> 6] = s;
    __syncthreads();
    s = red2[0] + red2[1] + red2[2] + red2[3];
    const float inv = 1.f / s;
#pragma unroll
    for (int i = 0; i < 8; i++) p[t + i * 256] = f2bf(v[i] * inv);
}

extern "C" void kernel_launch(void* const* d_in, const int* in_sizes, int n_in,
                              void* d_out, int out_size, void* d_ws, size_t ws_size,
                              hipStream_t stream) {
    const float* x = (const float*)d_in[0];     // [4,2048,768]
    const float* w = (const float*)d_in[1];     // [3,768,768]
    float* out = (float*)d_out;                 // [4,2048,768]

    const long NX = 6291456L;   // 4*2048*768
    const long NS = 16777216L;  // 4*2048*2048

    // layout: [Sb: NS] [Qb: NX] [Kb: NX] [Vb: NX] [Vt: NX]   (~84 MB)
    // xb+wt overlay the Sb region (dead before GEMM2 writes Sb)
    u16* Sb = (u16*)d_ws;
    u16* xb = Sb;                 // NX
    u16* wt = Sb + NX;            // 1769472  (NX+1769472 = 8060928 < NS)
    u16* Qb = Sb + NS;
    u16* Kb = Qb + NX;
    u16* Vb = Kb + NX;
    u16* Vt = Vb + NX;

    // 1. convert x -> bf16
    cvt_x_kernel<<<6144, 256, 0, stream>>>((const float4*)x, (ushort4*)xb, 1572864);
    // 2. convert + transpose W -> Wt[2304][768]
    cvt_w_kernel<<<dim3(24, 24, 3), dim3(32, 8), 0, stream>>>(w, wt);
    // 3. QKV: [8192,768] x [2304,768]^T -> Qb,Kb,Vb bf16
    gemm_bt_kernel<0><<<dim3(64, 18, 1), 256, 0, stream>>>(
        xb, wt, Qb, nullptr, 768, 0L, 0L, 0L, 768, 1.0f);
    // 4. V -> Vt[4][768][2048]
    transpose_v_kernel<<<dim3(64, 24, 4), dim3(32, 8), 0, stream>>>(Vb, Vt);
    // 5. scores: Q x K^T / sqrt(300) -> Sb bf16
    gemm_bt_kernel<1><<<dim3(16, 16, 4), 256, 0, stream>>>(
        Qb, Kb, Sb, nullptr, 768, 2048L * 768, 2048L * 768, 2048L * 2048, 2048,
        0.057735026918962574f);
    // 6. softmax rows (in place)
    softmax_kernel<<<8192, 256, 0, stream>>>(Sb);
    // 7. out = attn x Vt^T -> fp32
    gemm_bt_kernel<2><<<dim3(16, 6, 4), 256, 0, stream>>>(
        Sb, Vt, nullptr, out, 2048, 2048L * 2048, 768L * 2048, 2048L * 768, 768, 1.0f);
}

// Round 2
// 214.571 us; speedup vs baseline: 1.0062x; 1.0062x over previous
//
#include <hip/hip_runtime.h>

typedef unsigned short u16;
typedef __attribute__((ext_vector_type(8))) short bf16x8;
typedef __attribute__((ext_vector_type(4))) float f32x4;

#define BK 64

__device__ __forceinline__ u16 f2bf(float f) {
    unsigned u = __float_as_uint(f);
    unsigned r = u + 0x7fffu + ((u >> 16) & 1u);
    return (u16)(r >> 16);
}
__device__ __forceinline__ float bf2f(u16 h) {
    return __uint_as_float(((unsigned)h) << 16);
}

__device__ __forceinline__ void gload_lds16(const u16* g, u16* l) {
    __builtin_amdgcn_global_load_lds(
        (__attribute__((address_space(1))) unsigned int*)(u16*)g,
        (__attribute__((address_space(3))) unsigned int*)l,
        16, 0, 0);
}

// ---------- conversions ----------
__global__ __launch_bounds__(256) void cvt_x_kernel(const float4* __restrict__ x,
                                                    ushort4* __restrict__ o, int n4) {
    int i = blockIdx.x * 256 + threadIdx.x;
    if (i < n4) {
        float4 f = x[i];
        ushort4 u;
        u.x = f2bf(f.x); u.y = f2bf(f.y); u.z = f2bf(f.z); u.w = f2bf(f.w);
        o[i] = u;
    }
}

// kernel[3][768][768] fp32 -> Wt[3*768][768] bf16 where Wt[j*768+o][d] = W[j][d][o]
__global__ __launch_bounds__(256) void cvt_w_kernel(const float* __restrict__ W,
                                                    u16* __restrict__ Wt) {
    __shared__ float t[32][33];
    const int j = blockIdx.z;
    const int d0 = blockIdx.x * 32, o0 = blockIdx.y * 32;
    const int tx = threadIdx.x, ty = threadIdx.y;
#pragma unroll
    for (int i = 0; i < 4; i++) {
        int d = d0 + ty + i * 8;
        t[ty + i * 8][tx] = W[((long)j * 768 + d) * 768 + o0 + tx];
    }
    __syncthreads();
#pragma unroll
    for (int i = 0; i < 4; i++) {
        int o = o0 + ty + i * 8;
        Wt[((long)j * 768 + o) * 768 + d0 + tx] = f2bf(t[tx][ty + i * 8]);
    }
}

// V[4*2048][768] bf16 -> Vt[4][768][2048] bf16
__global__ __launch_bounds__(256) void transpose_v_kernel(const u16* __restrict__ V,
                                                          u16* __restrict__ Vt) {
    __shared__ u16 t[32][33];
    const int b = blockIdx.z;
    const int s0 = blockIdx.x * 32, o0 = blockIdx.y * 32;
    const int tx = threadIdx.x, ty = threadIdx.y;
#pragma unroll
    for (int i = 0; i < 4; i++) {
        int s = s0 + ty + i * 8;
        t[ty + i * 8][tx] = V[((long)b * 2048 + s) * 768 + o0 + tx];
    }
    __syncthreads();
#pragma unroll
    for (int i = 0; i < 4; i++) {
        int o = o0 + ty + i * 8;
        Vt[((long)b * 768 + o) * 2048 + s0 + tx] = t[tx][ty + i * 8];
    }
}

// ---------- GEMM: C = A(MxK) * Bt(NxK)^T, bf16 in, fp32 acc ----------
// TM = m-fragments per wave (2 -> BM=64, 4 -> BM=128). BN fixed at 128.
// MODE 0: QKV epilogue -> bf16 into Q/K/V (contiguous segments of 6291456)
// MODE 1: scores -> bf16, scaled
// MODE 2: PV -> fp32 out
template <int MODE, int TM>
__global__ __launch_bounds__(256)
void gemm_bt_kernel(const u16* __restrict__ A, const u16* __restrict__ Bt,
                    u16* __restrict__ o16, float* __restrict__ o32,
                    int K, long sA, long sB, long sO, int ldc, float scale) {
    constexpr int BM = TM * 32;
    __shared__ u16 As[BM * BK];
    __shared__ u16 Bs[128 * BK];

    const int tid = threadIdx.x;
    const int lane = tid & 63;
    const int wave = tid >> 6;
    const int z = blockIdx.z;

    const u16* Ab = A + (long)z * sA + (long)blockIdx.x * BM * K;
    const u16* Bb = Bt + (long)z * sB + (long)blockIdx.y * 128 * K;

    const int rl = lane >> 3;   // row within 8-row staging group
    const int pc = lane & 7;    // 16B chunk position within row
    const int q = lane >> 4;    // quad
    const int rA = lane & 15;
    const int wm = (wave >> 1) * (TM * 16);
    const int wn = (wave & 1) * 64;

    f32x4 acc[TM][4];
    const f32x4 zero = {0.f, 0.f, 0.f, 0.f};
#pragma unroll
    for (int i = 0; i < TM; i++)
#pragma unroll
        for (int j = 0; j < 4; j++) acc[i][j] = zero;

    for (int k0 = 0; k0 < K; k0 += BK) {
        // stage BMx64 A-tile and 128x64 B-tile via async global->LDS, 16B/lane
        // XOR swizzle: LDS row r position p holds global chunk p^(r&7)
#pragma unroll
        for (int t = 0; t < TM; ++t) {
            const int issue = wave + t * 4;      // wave-uniform
            const int row = issue * 8 + rl;
            const int gc = pc ^ (row & 7);
            gload_lds16(Ab + (long)row * K + k0 + gc * 8, &As[issue * 512]);
        }
#pragma unroll
        for (int t = 0; t < 4; ++t) {
            const int issue = wave + t * 4;
            const int row = issue * 8 + rl;
            const int gc = pc ^ (row & 7);
            gload_lds16(Bb + (long)row * K + k0 + gc * 8, &Bs[issue * 512]);
        }
        __syncthreads();
#pragma unroll
        for (int kk = 0; kk < BK; kk += 32) {
            const int gchunk = (kk >> 3) + q;    // desired global chunk index
            bf16x8 af[TM], bfr[4];
#pragma unroll
            for (int mi = 0; mi < TM; ++mi) {
                const int R = wm + mi * 16 + rA;
                af[mi] = *(const bf16x8*)&As[R * 64 + ((gchunk ^ (R & 7)) << 3)];
            }
#pragma unroll
            for (int ni = 0; ni < 4; ++ni) {
                const int R = wn + ni * 16 + rA;
                bfr[ni] = *(const bf16x8*)&Bs[R * 64 + ((gchunk ^ (R & 7)) << 3)];
            }
#pragma unroll
            for (int mi = 0; mi < TM; ++mi)
#pragma unroll
                for (int ni = 0; ni < 4; ++ni)
                    acc[mi][ni] = __builtin_amdgcn_mfma_f32_16x16x32_bf16(
                        af[mi], bfr[ni], acc[mi][ni], 0, 0, 0);
        }
        __syncthreads();
    }

    // epilogue: C/D layout col=lane&15, row=quad*4+reg
    const int rowb = blockIdx.x * BM + wm + q * 4;
    const int colb = blockIdx.y * 128 + wn + rA;
#pragma unroll
    for (int mi = 0; mi < TM; ++mi) {
#pragma unroll
        for (int ni = 0; ni < 4; ++ni) {
            const int col = colb + ni * 16;
#pragma unroll
            for (int r = 0; r < 4; ++r) {
                const int row = rowb + mi * 16 + r;
                const float v = acc[mi][ni][r];
                if (MODE == 0) {
                    const int seg = col / 768;  // block-uniform (tileN=128 divides 768)
                    o16[(long)seg * 6291456 + (long)row * ldc + (col - seg * 768)] = f2bf(v);
                } else if (MODE == 1) {
                    u16* dst = o16 + (long)z * sO;
                    dst[(long)row * ldc + col] = f2bf(v * scale);
                } else {
                    float* dst = o32 + (long)z * sO;
                    dst[(long)row * ldc + col] = v;
                }
            }
        }
    }
}

// ---------- softmax over rows of S[8192][2048] (bf16, in place) ----------
// 256 threads/row, 8 contiguous u16 (one uint4) per thread.
__global__ __launch_bounds__(256) void softmax_kernel(u16* __restrict__ S) {
    const long row = blockIdx.x;
    uint4* p = (uint4*)(S + row * 2048) + threadIdx.x;
    const int t = threadIdx.x;
    uint4 u = *p;
    float v[8];
    v[0] = bf2f((u16)(u.x & 0xffff)); v[1] = bf2f((u16)(u.x >> 16));
    v[2] = bf2f((u16)(u.y & 0xffff)); v[3] = bf2f((u16)(u.y >> 16));
    v[4] = bf2f((u16)(u.z & 0xffff)); v[5] = bf2f((u16)(u.z >> 16));
    v[6] = bf2f((u16)(u.w & 0xffff)); v[7] = bf2f((u16)(u.w >> 16));
    float mx = -1e30f;
#pragma unroll
    for (int i = 0; i < 8; i++) mx = fmaxf(mx, v[i]);
#pragma unroll
    for (int off = 32; off >= 1; off >>= 1) mx = fmaxf(mx, __shfl_xor(mx, off));
    __shared__ float red[4], red2[4];
    if ((t & 63) == 0) red[t >> 6] = mx;
    __syncthreads();
    mx = fmaxf(fmaxf(red[0], red[1]), fmaxf(red[2], red[3]));
    float s = 0.f;
#pragma unroll
    for (int i = 0; i < 8; i++) {
        v[i] = __expf(v[i] - mx);
        s += v[i];
    }
#pragma unroll
    for (int off = 32; off >= 1; off >>= 1) s += __shfl_xor(s, off);
    if ((t & 63) == 0) red2[t >> 6] = s;
    __syncthreads();
    s = red2[0] + red2[1] + red2[2] + red2[3];
    const float inv = 1.f / s;
#pragma unroll
    for (int i = 0; i < 8; i++) {
        unsigned b = f2bf(v[i] * inv);
        if (i & 1) {
            ((unsigned*)&u)[i >> 1] |= b << 16;
        } else {
            ((unsigned*)&u)[i >> 1] = b;
        }
    }
    *p = u;
}

extern "C" void kernel_launch(void* const* d_in, const int* in_sizes, int n_in,
                              void* d_out, int out_size, void* d_ws, size_t ws_size,
                              hipStream_t stream) {
    const float* x = (const float*)d_in[0];     // [4,2048,768]
    const float* w = (const float*)d_in[1];     // [3,768,768]
    float* out = (float*)d_out;                 // [4,2048,768]

    const long NX = 6291456L;   // 4*2048*768
    const long NS = 16777216L;  // 4*2048*2048

    // layout: [Sb: NS] [Qb: NX] [Kb: NX] [Vb: NX] [Vt: NX]   (~84 MB)
    // xb+wt overlay the Sb region (dead before GEMM2 writes Sb)
    u16* Sb = (u16*)d_ws;
    u16* xb = Sb;                 // NX
    u16* wt = Sb + NX;            // 1769472  (NX+1769472 = 8060928 < NS)
    u16* Qb = Sb + NS;
    u16* Kb = Qb + NX;
    u16* Vb = Kb + NX;
    u16* Vt = Vb + NX;

    // 1. convert x -> bf16
    cvt_x_kernel<<<6144, 256, 0, stream>>>((const float4*)x, (ushort4*)xb, 1572864);
    // 2. convert + transpose W -> Wt[2304][768]
    cvt_w_kernel<<<dim3(24, 24, 3), dim3(32, 8), 0, stream>>>(w, wt);
    // 3. QKV: [8192,768] x [2304,768]^T -> Qb,Kb,Vb bf16  (1152 blocks)
    gemm_bt_kernel<0, 4><<<dim3(64, 18, 1), 256, 0, stream>>>(
        xb, wt, Qb, nullptr, 768, 0L, 0L, 0L, 768, 1.0f);
    // 4. V -> Vt[4][768][2048]
    transpose_v_kernel<<<dim3(64, 24, 4), dim3(32, 8), 0, stream>>>(Vb, Vt);
    // 5. scores: Q x K^T / sqrt(300) -> Sb bf16  (1024 blocks, 4/CU)
    gemm_bt_kernel<1, 4><<<dim3(16, 16, 4), 256, 0, stream>>>(
        Qb, Kb, Sb, nullptr, 768, 2048L * 768, 2048L * 768, 2048L * 2048, 2048,
        0.057735026918962574f);
    // 6. softmax rows (in place)
    softmax_kernel<<<8192, 256, 0, stream>>>(Sb);
    // 7. out = attn x Vt^T -> fp32   (BM=64 -> 768 blocks = 3.0/CU exact)
    gemm_bt_kernel<2, 2><<<dim3(32, 6, 4), 256, 0, stream>>>(
        Sb, Vt, nullptr, out, 2048, 2048L * 2048, 768L * 2048, 2048L * 768, 768, 1.0f);
}

// Round 3
// 211.338 us; speedup vs baseline: 1.0215x; 1.0153x over previous
//
#include <hip/hip_runtime.h>

typedef unsigned short u16;
typedef __attribute__((ext_vector_type(8))) short bf16x8;
typedef __attribute__((ext_vector_type(4))) float f32x4;

#define BK 64

__device__ __forceinline__ u16 f2bf(float f) {
    unsigned u = __float_as_uint(f);
    unsigned r = u + 0x7fffu + ((u >> 16) & 1u);
    return (u16)(r >> 16);
}
__device__ __forceinline__ float bf2f(u16 h) {
    return __uint_as_float(((unsigned)h) << 16);
}

__device__ __forceinline__ void gload_lds16(const u16* g, u16* l) {
    __builtin_amdgcn_global_load_lds(
        (__attribute__((address_space(1))) unsigned int*)(u16*)g,
        (__attribute__((address_space(3))) unsigned int*)l,
        16, 0, 0);
}

// ---------- fused input conversion ----------
// blocks [0,6144): x fp32 -> bf16 (float4/thread)
// blocks [6144,7872): kernel[3][768][768] fp32 -> Wt[j*768+o][d] bf16 (transpose)
__global__ __launch_bounds__(256) void cvt_in_kernel(const float* __restrict__ x,
                                                     const float* __restrict__ W,
                                                     u16* __restrict__ xb,
                                                     u16* __restrict__ Wt) {
    const int bid = blockIdx.x;
    const int tid = threadIdx.x;
    if (bid < 6144) {
        int i = bid * 256 + tid;
        float4 f = ((const float4*)x)[i];
        ushort4 u;
        u.x = f2bf(f.x); u.y = f2bf(f.y); u.z = f2bf(f.z); u.w = f2bf(f.w);
        ((ushort4*)xb)[i] = u;
    } else {
        __shared__ float t[32][33];
        const int b = bid - 6144;
        const int j = b / 576;
        const int rem = b - j * 576;
        const int d0 = (rem % 24) * 32, o0 = (rem / 24) * 32;
        const int tx = tid & 31, ty = tid >> 5;
#pragma unroll
        for (int i = 0; i < 4; i++) {
            int d = d0 + ty + i * 8;
            t[ty + i * 8][tx] = W[((long)j * 768 + d) * 768 + o0 + tx];
        }
        __syncthreads();
#pragma unroll
        for (int i = 0; i < 4; i++) {
            int o = o0 + ty + i * 8;
            Wt[((long)j * 768 + o) * 768 + d0 + tx] = f2bf(t[tx][ty + i * 8]);
        }
    }
}

// ---------- GEMM: C = A(MxK) * Bt(NxK)^T, bf16 in, fp32 acc ----------
// TM = m-fragments per wave (2 -> BM=64, 4 -> BM=128). BN fixed at 128.
// MODE 0: QKV epilogue -> bf16 into Q/K/V (contiguous segments of 6291456)
// MODE 1: scores -> bf16, scaled
// MODE 2: PV -> fp32 out
template <int MODE, int TM>
__global__ __launch_bounds__(256)
void gemm_bt_kernel(const u16* __restrict__ A, const u16* __restrict__ Bt,
                    u16* __restrict__ o16, float* __restrict__ o32,
                    int K, long sA, long sB, long sO, int ldc, float scale) {
    constexpr int BM = TM * 32;
    __shared__ u16 As[BM * BK];
    __shared__ u16 Bs[128 * BK];

    const int tid = threadIdx.x;
    const int lane = tid & 63;
    const int wave = tid >> 6;
    const int z = blockIdx.z;

    const u16* Ab = A + (long)z * sA + (long)blockIdx.x * BM * K;
    const u16* Bb = Bt + (long)z * sB + (long)blockIdx.y * 128 * K;

    const int rl = lane >> 3;   // row within 8-row staging group
    const int pc = lane & 7;    // 16B chunk position within row
    const int q = lane >> 4;    // quad
    const int rA = lane & 15;
    const int wm = (wave >> 1) * (TM * 16);
    const int wn = (wave & 1) * 64;

    f32x4 acc[TM][4];
    const f32x4 zero = {0.f, 0.f, 0.f, 0.f};
#pragma unroll
    for (int i = 0; i < TM; i++)
#pragma unroll
        for (int j = 0; j < 4; j++) acc[i][j] = zero;

    for (int k0 = 0; k0 < K; k0 += BK) {
        // stage BMx64 A-tile and 128x64 B-tile via async global->LDS, 16B/lane
        // XOR swizzle: LDS row r position p holds global chunk p^(r&7)
#pragma unroll
        for (int t = 0; t < TM; ++t) {
            const int issue = wave + t * 4;      // wave-uniform
            const int row = issue * 8 + rl;
            const int gc = pc ^ (row & 7);
            gload_lds16(Ab + (long)row * K + k0 + gc * 8, &As[issue * 512]);
        }
#pragma unroll
        for (int t = 0; t < 4; ++t) {
            const int issue = wave + t * 4;
            const int row = issue * 8 + rl;
            const int gc = pc ^ (row & 7);
            gload_lds16(Bb + (long)row * K + k0 + gc * 8, &Bs[issue * 512]);
        }
        __syncthreads();
#pragma unroll
        for (int kk = 0; kk < BK; kk += 32) {
            const int gchunk = (kk >> 3) + q;    // desired global chunk index
            bf16x8 af[TM], bfr[4];
#pragma unroll
            for (int mi = 0; mi < TM; ++mi) {
                const int R = wm + mi * 16 + rA;
                af[mi] = *(const bf16x8*)&As[R * 64 + ((gchunk ^ (R & 7)) << 3)];
            }
#pragma unroll
            for (int ni = 0; ni < 4; ++ni) {
                const int R = wn + ni * 16 + rA;
                bfr[ni] = *(const bf16x8*)&Bs[R * 64 + ((gchunk ^ (R & 7)) << 3)];
            }
#pragma unroll
            for (int mi = 0; mi < TM; ++mi)
#pragma unroll
                for (int ni = 0; ni < 4; ++ni)
                    acc[mi][ni] = __builtin_amdgcn_mfma_f32_16x16x32_bf16(
                        af[mi], bfr[ni], acc[mi][ni], 0, 0, 0);
        }
        __syncthreads();
    }

    // epilogue: C/D layout col=lane&15, row=quad*4+reg
    const int rowb = blockIdx.x * BM + wm + q * 4;
    const int colb = blockIdx.y * 128 + wn + rA;
#pragma unroll
    for (int mi = 0; mi < TM; ++mi) {
#pragma unroll
        for (int ni = 0; ni < 4; ++ni) {
            const int col = colb + ni * 16;
#pragma unroll
            for (int r = 0; r < 4; ++r) {
                const int row = rowb + mi * 16 + r;
                const float v = acc[mi][ni][r];
                if (MODE == 0) {
                    const int seg = col / 768;  // block-uniform (tileN=128 divides 768)
                    o16[(long)seg * 6291456 + (long)row * ldc + (col - seg * 768)] = f2bf(v);
                } else if (MODE == 1) {
                    u16* dst = o16 + (long)z * sO;
                    dst[(long)row * ldc + col] = f2bf(v * scale);
                } else {
                    float* dst = o32 + (long)z * sO;
                    dst[(long)row * ldc + col] = v;
                }
            }
        }
    }
}

// ---------- fused: softmax rows of S[8192][2048] (in place) + V transpose ----------
// blocks [0,8192): softmax row = bid (256 thr, one uint4 of 8 bf16 each)
// blocks [8192,14336): V[4*2048][768] -> Vt[4][768][2048]
__global__ __launch_bounds__(256) void post_kernel(u16* __restrict__ S,
                                                   const u16* __restrict__ V,
                                                   u16* __restrict__ Vt) {
    const int bid = blockIdx.x;
    const int t = threadIdx.x;
    if (bid < 8192) {
        uint4* p = (uint4*)(S + (long)bid * 2048) + t;
        uint4 u = *p;
        float v[8];
        v[0] = bf2f((u16)(u.x & 0xffff)); v[1] = bf2f((u16)(u.x >> 16));
        v[2] = bf2f((u16)(u.y & 0xffff)); v[3] = bf2f((u16)(u.y >> 16));
        v[4] = bf2f((u16)(u.z & 0xffff)); v[5] = bf2f((u16)(u.z >> 16));
        v[6] = bf2f((u16)(u.w & 0xffff)); v[7] = bf2f((u16)(u.w >> 16));
        float mx = -1e30f;
#pragma unroll
        for (int i = 0; i < 8; i++) mx = fmaxf(mx, v[i]);
#pragma unroll
        for (int off = 32; off >= 1; off >>= 1) mx = fmaxf(mx, __shfl_xor(mx, off));
        __shared__ float red[4], red2[4];
        if ((t & 63) == 0) red[t >> 6] = mx;
        __syncthreads();
        mx = fmaxf(fmaxf(red[0], red[1]), fmaxf(red[2], red[3]));
        float s = 0.f;
#pragma unroll
        for (int i = 0; i < 8; i++) {
            v[i] = __expf(v[i] - mx);
            s += v[i];
        }
#pragma unroll
        for (int off = 32; off >= 1; off >>= 1) s += __shfl_xor(s, off);
        if ((t & 63) == 0) red2[t >> 6] = s;
        __syncthreads();
        s = red2[0] + red2[1] + red2[2] + red2[3];
        const float inv = 1.f / s;
#pragma unroll
        for (int i = 0; i < 8; i++) {
            unsigned b = f2bf(v[i] * inv);
            if (i & 1) ((unsigned*)&u)[i >> 1] |= b << 16;
            else       ((unsigned*)&u)[i >> 1] = b;
        }
        *p = u;
    } else {
        __shared__ u16 tt[32][33];
        const int b = bid - 8192;
        const int bz = b / 1536;
        const int rem = b - bz * 1536;
        const int s0 = (rem & 63) * 32, o0 = (rem >> 6) * 32;
        const int tx = t & 31, ty = t >> 5;
#pragma unroll
        for (int i = 0; i < 4; i++) {
            int s = s0 + ty + i * 8;
            tt[ty + i * 8][tx] = V[((long)bz * 2048 + s) * 768 + o0 + tx];
        }
        __syncthreads();
#pragma unroll
        for (int i = 0; i < 4; i++) {
            int o = o0 + ty + i * 8;
            Vt[((long)bz * 768 + o) * 2048 + s0 + tx] = tt[tx][ty + i * 8];
        }
    }
}

extern "C" void kernel_launch(void* const* d_in, const int* in_sizes, int n_in,
                              void* d_out, int out_size, void* d_ws, size_t ws_size,
                              hipStream_t stream) {
    const float* x = (const float*)d_in[0];     // [4,2048,768]
    const float* w = (const float*)d_in[1];     // [3,768,768]
    float* out = (float*)d_out;                 // [4,2048,768]

    const long NX = 6291456L;   // 4*2048*768
    const long NS = 16777216L;  // 4*2048*2048

    // layout: [Sb: NS] [Qb: NX] [Kb: NX] [Vb: NX] [Vt: NX]   (~84 MB)
    // xb+wt overlay the Sb region (dead before GEMM2 writes Sb)
    u16* Sb = (u16*)d_ws;
    u16* xb = Sb;                 // NX
    u16* wt = Sb + NX;            // 1769472  (NX+1769472 = 8060928 < NS)
    u16* Qb = Sb + NS;
    u16* Kb = Qb + NX;
    u16* Vb = Kb + NX;
    u16* Vt = Vb + NX;

    // 1. convert x -> bf16 AND convert+transpose W -> Wt[2304][768] (fused)
    cvt_in_kernel<<<7872, 256, 0, stream>>>(x, w, xb, wt);
    // 2. QKV: [8192,768] x [2304,768]^T -> Qb,Kb,Vb bf16
    //    BM=64 -> grid 128x18 = 2304 blocks = 9.0/CU exact
    gemm_bt_kernel<0, 2><<<dim3(128, 18, 1), 256, 0, stream>>>(
        xb, wt, Qb, nullptr, 768, 0L, 0L, 0L, 768, 1.0f);
    // 3. scores: Q x K^T / sqrt(300) -> Sb bf16
    //    BM=64 -> grid 32x16x4 = 2048 blocks = 8.0/CU exact
    gemm_bt_kernel<1, 2><<<dim3(32, 16, 4), 256, 0, stream>>>(
        Qb, Kb, Sb, nullptr, 768, 2048L * 768, 2048L * 768, 2048L * 2048, 2048,
        0.057735026918962574f);
    // 4. softmax rows (in place) + V -> Vt (fused; Vt only needed by step 5)
    post_kernel<<<14336, 256, 0, stream>>>(Sb, Vb, Vt);
    // 5. out = attn x Vt^T -> fp32   (BM=64 -> 768 blocks = 3.0/CU exact)
    gemm_bt_kernel<2, 2><<<dim3(32, 6, 4), 256, 0, stream>>>(
        Sb, Vt, nullptr, out, 2048, 2048L * 2048, 768L * 2048, 2048L * 768, 768, 1.0f);
}

// Round 4
// 195.122 us; speedup vs baseline: 1.1064x; 1.0831x over previous
//
#include <hip/hip_runtime.h>

typedef unsigned short u16;
typedef __attribute__((ext_vector_type(8))) short bf16x8;
typedef __attribute__((ext_vector_type(4))) float f32x4;

#define BK 64

__device__ __forceinline__ u16 f2bf(float f) {
    unsigned u = __float_as_uint(f);
    unsigned r = u + 0x7fffu + ((u >> 16) & 1u);
    return (u16)(r >> 16);
}
__device__ __forceinline__ float bf2f(u16 h) {
    return __uint_as_float(((unsigned)h) << 16);
}

__device__ __forceinline__ void gload_lds16(const u16* g, u16* l) {
    __builtin_amdgcn_global_load_lds(
        (__attribute__((address_space(1))) unsigned int*)(u16*)g,
        (__attribute__((address_space(3))) unsigned int*)l,
        16, 0, 0);
}

// ---------- fused input conversion + rowsum zeroing ----------
// blocks [0,6144): x fp32 -> bf16 (float4/thread)
// blocks [6144,7872): kernel[3][768][768] fp32 -> Wt[j*768+o][d] bf16 (transpose)
// block 7872: zero rowsum[8192]
__global__ __launch_bounds__(256) void cvt_in_kernel(const float* __restrict__ x,
                                                     const float* __restrict__ W,
                                                     u16* __restrict__ xb,
                                                     u16* __restrict__ Wt,
                                                     float* __restrict__ rsum) {
    const int bid = blockIdx.x;
    const int tid = threadIdx.x;
    if (bid < 6144) {
        int i = bid * 256 + tid;
        float4 f = ((const float4*)x)[i];
        ushort4 u;
        u.x = f2bf(f.x); u.y = f2bf(f.y); u.z = f2bf(f.z); u.w = f2bf(f.w);
        ((ushort4*)xb)[i] = u;
    } else if (bid < 7872) {
        __shared__ float t[32][33];
        const int b = bid - 6144;
        const int j = b / 576;
        const int rem = b - j * 576;
        const int d0 = (rem % 24) * 32, o0 = (rem / 24) * 32;
        const int tx = tid & 31, ty = tid >> 5;
#pragma unroll
        for (int i = 0; i < 4; i++) {
            int d = d0 + ty + i * 8;
            t[ty + i * 8][tx] = W[((long)j * 768 + d) * 768 + o0 + tx];
        }
        __syncthreads();
#pragma unroll
        for (int i = 0; i < 4; i++) {
            int o = o0 + ty + i * 8;
            Wt[((long)j * 768 + o) * 768 + d0 + tx] = f2bf(t[tx][ty + i * 8]);
        }
    } else {
        const float4 z4 = {0.f, 0.f, 0.f, 0.f};
#pragma unroll
        for (int j = 0; j < 8; j++) ((float4*)rsum)[tid * 8 + j] = z4;
    }
}

// ---------- GEMM: C = A(MxK) * Bt(NxK)^T, bf16 in, fp32 acc ----------
// TM=2 (BM=64); BN=128.
// MODE 0: QKV. y<12 -> Q/K bf16 direct; y>=12 -> V written TRANSPOSED (Vt) via LDS.
// MODE 1: P~ = exp(s*scale) bf16 + per-row atomic sum into rsum.
// MODE 2: out = acc / rsum[row] -> fp32.
template <int MODE, int TM>
__global__ __launch_bounds__(256)
void gemm_bt_kernel(const u16* __restrict__ A, const u16* __restrict__ Bt,
                    u16* __restrict__ o16, float* __restrict__ o32,
                    u16* __restrict__ vt, float* __restrict__ rsum,
                    int K, long sA, long sB, long sO, int ldc, float scale) {
    constexpr int BM = TM * 32;
    __shared__ u16 smem[BM * BK + 128 * BK];   // staging; reused for V transpose
    u16* As = smem;
    u16* Bs = smem + BM * BK;

    const int tid = threadIdx.x;
    const int lane = tid & 63;
    const int wave = tid >> 6;
    const int z = blockIdx.z;

    const u16* Ab = A + (long)z * sA + (long)blockIdx.x * BM * K;
    const u16* Bb = Bt + (long)z * sB + (long)blockIdx.y * 128 * K;

    const int rl = lane >> 3;   // row within 8-row staging group
    const int pc = lane & 7;    // 16B chunk position within row
    const int q = lane >> 4;    // quad
    const int rA = lane & 15;
    const int wm = (wave >> 1) * (TM * 16);
    const int wn = (wave & 1) * 64;

    f32x4 acc[TM][4];
    const f32x4 zero = {0.f, 0.f, 0.f, 0.f};
#pragma unroll
    for (int i = 0; i < TM; i++)
#pragma unroll
        for (int j = 0; j < 4; j++) acc[i][j] = zero;

    for (int k0 = 0; k0 < K; k0 += BK) {
        // XOR swizzle: LDS row r position p holds global chunk p^(r&7)
#pragma unroll
        for (int t = 0; t < TM; ++t) {
            const int issue = wave + t * 4;      // wave-uniform
            const int row = issue * 8 + rl;
            const int gc = pc ^ (row & 7);
            gload_lds16(Ab + (long)row * K + k0 + gc * 8, &As[issue * 512]);
        }
#pragma unroll
        for (int t = 0; t < 4; ++t) {
            const int issue = wave + t * 4;
            const int row = issue * 8 + rl;
            const int gc = pc ^ (row & 7);
            gload_lds16(Bb + (long)row * K + k0 + gc * 8, &Bs[issue * 512]);
        }
        __syncthreads();
#pragma unroll
        for (int kk = 0; kk < BK; kk += 32) {
            const int gchunk = (kk >> 3) + q;
            bf16x8 af[TM], bfr[4];
#pragma unroll
            for (int mi = 0; mi < TM; ++mi) {
                const int R = wm + mi * 16 + rA;
                af[mi] = *(const bf16x8*)&As[R * 64 + ((gchunk ^ (R & 7)) << 3)];
            }
#pragma unroll
            for (int ni = 0; ni < 4; ++ni) {
                const int R = wn + ni * 16 + rA;
                bfr[ni] = *(const bf16x8*)&Bs[R * 64 + ((gchunk ^ (R & 7)) << 3)];
            }
#pragma unroll
            for (int mi = 0; mi < TM; ++mi)
#pragma unroll
                for (int ni = 0; ni < 4; ++ni)
                    acc[mi][ni] = __builtin_amdgcn_mfma_f32_16x16x32_bf16(
                        af[mi], bfr[ni], acc[mi][ni], 0, 0, 0);
        }
        __syncthreads();
    }

    // epilogue: C/D layout col=lane&15, row=quad*4+reg
    const int rowb = blockIdx.x * BM + wm + q * 4;
    const int colb = blockIdx.y * 128 + wn + rA;

    if (MODE == 0 && blockIdx.y >= 12) {
        // V segment -> write transposed (Vt[b][o][s]) via LDS tile [128 o][72 pad]
        u16* T = smem;
#pragma unroll
        for (int mi = 0; mi < TM; ++mi)
#pragma unroll
            for (int ni = 0; ni < 4; ++ni) {
                const int lc = wn + ni * 16 + rA;
#pragma unroll
                for (int r = 0; r < 4; ++r) {
                    const int lr = wm + mi * 16 + q * 4 + r;
                    T[lc * 72 + lr] = f2bf(acc[mi][ni][r]);
                }
            }
        __syncthreads();
        const int b = blockIdx.x >> 5;
        const int s0 = (blockIdx.x & 31) * 64;
        const int o0 = (blockIdx.y - 12) * 128;
        const int ol = tid >> 1, h = (tid & 1) * 32;
        u16* dst = vt + ((long)b * 768 + o0 + ol) * 2048 + s0 + h;
        const u16* src = &T[ol * 72 + h];
#pragma unroll
        for (int j = 0; j < 4; ++j)
            *(uint4*)(dst + j * 8) = *(const uint4*)(src + j * 8);
        return;
    }

#pragma unroll
    for (int mi = 0; mi < TM; ++mi) {
        if (MODE == 0) {
            const int seg = blockIdx.y / 6;           // 0=Q, 1=K (block-uniform)
            const int ocol = colb - seg * 768;
#pragma unroll
            for (int ni = 0; ni < 4; ++ni)
#pragma unroll
                for (int r = 0; r < 4; ++r)
                    o16[(long)seg * 6291456 + (long)(rowb + mi * 16 + r) * 768 +
                        ocol + ni * 16] = f2bf(acc[mi][ni][r]);
        } else if (MODE == 1) {
            u16* dst = o16 + (long)z * sO;
            float rs[4] = {0.f, 0.f, 0.f, 0.f};
#pragma unroll
            for (int ni = 0; ni < 4; ++ni)
#pragma unroll
                for (int r = 0; r < 4; ++r) {
                    const float p = __expf(acc[mi][ni][r] * scale);
                    const u16 pb = f2bf(p);
                    dst[(long)(rowb + mi * 16 + r) * ldc + colb + ni * 16] = pb;
                    rs[r] += bf2f(pb);
                }
#pragma unroll
            for (int r = 0; r < 4; ++r) {
#pragma unroll
                for (int off = 1; off <= 8; off <<= 1) rs[r] += __shfl_xor(rs[r], off);
                if (rA == 0)
                    atomicAdd(&rsum[z * 2048 + rowb + mi * 16 + r], rs[r]);
            }
        } else {
            float* dst = o32 + (long)z * sO;
            const float4 rs4 = *(const float4*)&rsum[z * 2048 + rowb + mi * 16];
            const float inv[4] = {1.f / rs4.x, 1.f / rs4.y, 1.f / rs4.z, 1.f / rs4.w};
#pragma unroll
            for (int ni = 0; ni < 4; ++ni)
#pragma unroll
                for (int r = 0; r < 4; ++r)
                    dst[(long)(rowb + mi * 16 + r) * ldc + colb + ni * 16] =
                        acc[mi][ni][r] * inv[r];
        }
    }
}

extern "C" void kernel_launch(void* const* d_in, const int* in_sizes, int n_in,
                              void* d_out, int out_size, void* d_ws, size_t ws_size,
                              hipStream_t stream) {
    const float* x = (const float*)d_in[0];     // [4,2048,768]
    const float* w = (const float*)d_in[1];     // [3,768,768]
    float* out = (float*)d_out;                 // [4,2048,768]

    const long NX = 6291456L;   // 4*2048*768
    const long NS = 16777216L;  // 4*2048*2048

    // layout: [Sb: NS][Qb: NX][Kb: NX][Vt: NX][rowsum: 8192 f32]  (~71.3 MB)
    // xb+wt overlay the Sb region (dead before GEMM2 writes Sb)
    u16* Sb = (u16*)d_ws;
    u16* xb = Sb;                 // NX
    u16* wt = Sb + NX;            // 1769472  (< NS)
    u16* Qb = Sb + NS;
    u16* Kb = Qb + NX;
    u16* Vt = Kb + NX;
    float* rowsum = (float*)(Vt + NX);

    // 1. x -> bf16; W -> Wt[2304][768] bf16 transposed; rowsum <- 0
    cvt_in_kernel<<<7873, 256, 0, stream>>>(x, w, xb, wt, rowsum);
    // 2. QKV: [8192,768] x [2304,768]^T; Q,K direct; V transposed into Vt
    gemm_bt_kernel<0, 2><<<dim3(128, 18, 1), 256, 0, stream>>>(
        xb, wt, Qb, nullptr, Vt, nullptr, 768, 0L, 0L, 0L, 768, 1.0f);
    // 3. P~ = exp(QK^T/sqrt(300)) bf16 -> Sb, + rowsum atomics
    gemm_bt_kernel<1, 2><<<dim3(32, 16, 4), 256, 0, stream>>>(
        Qb, Kb, Sb, nullptr, nullptr, rowsum, 768, 2048L * 768, 2048L * 768,
        2048L * 2048, 2048, 0.057735026918962574f);
    // 4. out = (P~ x Vt^T) / rowsum -> fp32
    gemm_bt_kernel<2, 2><<<dim3(32, 6, 4), 256, 0, stream>>>(
        Sb, Vt, nullptr, out, nullptr, rowsum, 2048, 2048L * 2048, 768L * 2048,
        2048L * 768, 768, 1.0f);
}